// Round 9
// baseline (678.252 us; speedup 1.0000x reference)
//
#include <hip/hip_runtime.h>

#define B_ 4
#define C_ 512
#define L_ 4096

typedef __attribute__((ext_vector_type(8))) short bf16x8;
typedef __attribute__((ext_vector_type(4))) float f32x4;

#define MFMA16(a, b, c) __builtin_amdgcn_mfma_f32_16x16x32_bf16(a, b, c, 0, 0, 0)

static __device__ __forceinline__ unsigned short f2bf_rne(float f) {
  unsigned u = __float_as_uint(f);
  u += 0x7FFFu + ((u >> 16) & 1u);  // round-to-nearest-even
  return (unsigned short)(u >> 16);
}
static __device__ __forceinline__ unsigned pack_rne(float a, float b) {
  return (unsigned)f2bf_rne(a) | ((unsigned)f2bf_rne(b) << 16);
}
static __device__ __forceinline__ float bflo2f(unsigned w) {
  return __uint_as_float(w << 16);
}
static __device__ __forceinline__ float bfhi2f(unsigned w) {
  return __uint_as_float(w & 0xFFFF0000u);
}

// async global -> LDS, 16 B/lane; LDS dest = wave-uniform base + lane*16.
static __device__ __forceinline__ void g2lds16(const unsigned short* g,
                                               unsigned short* l) {
  __builtin_amdgcn_global_load_lds(
      (const __attribute__((address_space(1))) unsigned int*)g,
      (__attribute__((address_space(3))) unsigned int*)l, 16, 0, 0);
}

#define BAR_() __builtin_amdgcn_s_barrier()
#define LGKM0_() asm volatile("s_waitcnt lgkmcnt(0)" ::: "memory")
#define VMW_(N) asm volatile("s_waitcnt vmcnt(" #N ")" ::: "memory")

// ---------------------------------------------------------------------------
// K0 (fused): z<8:  Q,K fp32 (C,L) -> Qt,Kt bf16 (L,C)   (64x64 LDS transpose)
//             z>=8: Vb[b,c,j] = bf16(V[b,c,j]*mask[b,j]) (streaming cast)
//             block (0,0,8) additionally zeroes rowsum (16384 floats).
// grid (64, 8, 12), block 256.  Branch is block-uniform.
// ---------------------------------------------------------------------------
__global__ __launch_bounds__(256) void prep_k(
    const float* __restrict__ Q, const float* __restrict__ K,
    const float* __restrict__ V, const float* __restrict__ mask,
    unsigned short* __restrict__ Qt, unsigned short* __restrict__ Kt,
    unsigned short* __restrict__ Vb, float* __restrict__ rowsum) {
  int zb = blockIdx.z;
  int t = threadIdx.x;
  __shared__ float tile[64][65];
  if (zb < 8) {
    int b = zb >> 1;
    const float* src = ((zb & 1) ? K : Q) + (size_t)b * C_ * L_;
    unsigned short* dst = ((zb & 1) ? Kt : Qt) + (size_t)b * L_ * C_;
    int i0 = blockIdx.x * 64, c0 = blockIdx.y * 64;
    int cr = t >> 2, ig = (t & 3) * 16;
    const float* s = src + (size_t)(c0 + cr) * L_ + i0 + ig;
#pragma unroll
    for (int q = 0; q < 4; ++q) {
      float4 v = *(const float4*)(s + 4 * q);
      tile[cr][ig + 4 * q + 0] = v.x;
      tile[cr][ig + 4 * q + 1] = v.y;
      tile[cr][ig + 4 * q + 2] = v.z;
      tile[cr][ig + 4 * q + 3] = v.w;
    }
    __syncthreads();
    int ir = t >> 2, cg = (t & 3) * 16;
    unsigned wds[8];
#pragma unroll
    for (int k = 0; k < 8; ++k)
      wds[k] = pack_rne(tile[cg + 2 * k][ir], tile[cg + 2 * k + 1][ir]);
    unsigned short* d = dst + (size_t)(i0 + ir) * C_ + c0 + cg;
    uint4 o0, o1;
    o0.x = wds[0]; o0.y = wds[1]; o0.z = wds[2]; o0.w = wds[3];
    o1.x = wds[4]; o1.y = wds[5]; o1.z = wds[6]; o1.w = wds[7];
    *(uint4*)d = o0;
    *(uint4*)(d + 8) = o1;
  } else {
    int b = zb - 8;
    int flat = blockIdx.x + (blockIdx.y << 6);  // 0..511
    if (b == 0 && flat == 0) {                  // zero rowsum (B_*L_ floats)
      float4 z4 = {0.f, 0.f, 0.f, 0.f};
#pragma unroll
      for (int q = 0; q < 16; ++q)
        *(float4*)(rowsum + (q * 256 + t) * 4) = z4;
    }
    size_t base = (size_t)b * C_ * L_ + (size_t)flat * 4096 + (size_t)t * 16;
    int j = (int)(base & (L_ - 1));  // 16-elem group stays within one row
    const float* vp = V + base;
    const float* mp = mask + (size_t)b * L_ + j;
#pragma unroll
    for (int g = 0; g < 2; ++g) {
      float4 v0 = *(const float4*)(vp + g * 8);
      float4 v1 = *(const float4*)(vp + g * 8 + 4);
      float4 m0 = *(const float4*)(mp + g * 8);
      float4 m1 = *(const float4*)(mp + g * 8 + 4);
      uint4 o;
      o.x = pack_rne(v0.x * m0.x, v0.y * m0.y);
      o.y = pack_rne(v0.z * m0.z, v0.w * m0.w);
      o.z = pack_rne(v1.x * m1.x, v1.y * m1.y);
      o.w = pack_rne(v1.z * m1.z, v1.w * m1.w);
      *(uint4*)(Vb + base + g * 8) = o;
    }
  }
}

// ===========================================================================
// 256x256 8-phase NT GEMM mainloop (round-3, verified) — used by gemm1.
// ===========================================================================
__device__ __forceinline__ void gemm_8phase(
    const unsigned short* __restrict__ Ab,
    const unsigned short* __restrict__ Bb, int lda, int ldb, int Kdim,
    unsigned short* sA, unsigned short* sB, f32x4 (&acc)[8][4]) {
  const int t = threadIdx.x;
  const int lane = t & 63;
  const int quad = lane >> 4;
  const int l15 = lane & 15;
  const int w = t >> 6;
  const int wm = (w & 1) * 128;
  const int wn = (w >> 1) * 64;
  const int et = (t * 8) ^ (((t >> 5) & 1) << 4);
  const int srw = et >> 5;
  const int scl = et & 31;
  const int nt = Kdim >> 6;

  auto stage = [&](int nom, int hh) {
    int st = nom < nt ? nom : nt - 1;
    int db = nom & 1;
    int h = hh & 1;
    const unsigned short* g;
    unsigned short* l;
    if (hh < 2) {
      g = Bb + (size_t)(h * 128 + srw) * ldb + st * 64 + scl;
      l = sB + db * 16384 + h * 4096 + t * 8;
    } else {
      g = Ab + (size_t)(h * 128 + srw) * lda + st * 64 + scl;
      l = sA + db * 16384 + h * 4096 + t * 8;
    }
    g2lds16(g, l);
    g2lds16(g + 32, l + 8192);
  };
  auto rd = [&](const unsigned short* s, int db, int kc, int row) -> bf16x8 {
    int e = db * 16384 + kc * 8192 + row * 32 + quad * 8;
    e ^= ((e >> 8) & 1) << 4;
    return *(const bf16x8*)(s + e);
  };

  bf16x8 aF[4][2], b0[2][2], b1[2][2];
  auto rdA4 = [&](int db, int mbase) {
#pragma unroll
    for (int m = 0; m < 4; ++m)
#pragma unroll
      for (int kc = 0; kc < 2; ++kc)
        aF[m][kc] = rd(sA, db, kc, wm + (mbase + m) * 16 + l15);
  };
  auto rdB2 = [&](bf16x8 (&bf)[2][2], int db, int nbase) {
#pragma unroll
    for (int n = 0; n < 2; ++n)
#pragma unroll
      for (int kc = 0; kc < 2; ++kc)
        bf[n][kc] = rd(sB, db, kc, wn + (nbase + n) * 16 + l15);
  };
  auto mfma8 = [&](bf16x8 (&bf)[2][2], int mo, int no) {
    __builtin_amdgcn_s_setprio(1);
#pragma unroll
    for (int m = 0; m < 4; ++m)
#pragma unroll
      for (int n = 0; n < 2; ++n) {
        acc[mo + m][no + n] = MFMA16(aF[m][0], bf[n][0], acc[mo + m][no + n]);
        acc[mo + m][no + n] = MFMA16(aF[m][1], bf[n][1], acc[mo + m][no + n]);
      }
    __builtin_amdgcn_s_setprio(0);
  };

  stage(0, 0); stage(0, 1); stage(0, 2); stage(0, 3);
  asm volatile("s_waitcnt vmcnt(4)" ::: "memory");
  stage(1, 0); stage(1, 1); stage(1, 2);
  asm volatile("s_waitcnt vmcnt(6)" ::: "memory");
  BAR_();

  const int ni = nt >> 1;
  for (int i = 0; i < ni; ++i) {
    const int X = 2 * i;
    rdA4(0, 0); rdB2(b0, 0, 0); rdB2(b1, 0, 2);
    stage(X + 1, 3);
    BAR_(); LGKM0_();
    mfma8(b0, 0, 0);
    BAR_();
    stage(X + 2, 0);
    BAR_();
    mfma8(b1, 0, 2);
    BAR_();
    rdA4(0, 4);
    stage(X + 2, 1);
    BAR_(); LGKM0_();
    mfma8(b0, 4, 0);
    BAR_();
    stage(X + 2, 2);
    VMW_(6); BAR_();
    mfma8(b1, 4, 2);
    BAR_(); __builtin_amdgcn_sched_barrier(0);
    rdA4(1, 0); rdB2(b0, 1, 0); rdB2(b1, 1, 2);
    stage(X + 2, 3);
    BAR_(); LGKM0_();
    mfma8(b0, 0, 0);
    BAR_();
    stage(X + 3, 0);
    BAR_();
    mfma8(b1, 0, 2);
    BAR_();
    rdA4(1, 4);
    stage(X + 3, 1);
    BAR_(); LGKM0_();
    mfma8(b0, 4, 0);
    BAR_();
    stage(X + 3, 2);
    VMW_(6); BAR_();
    mfma8(b1, 4, 2);
    BAR_(); __builtin_amdgcn_sched_barrier(0);
  }
  asm volatile("s_waitcnt vmcnt(0)" ::: "memory");
}

// ---------------------------------------------------------------------------
// K1 (8-phase): E = Qt*Kt^T; tv = exp(E*scale + log(mask+1e-6));
// tb = bf16(tv*mask); fp32 rowsum atomics.  grid (16,16,4), block 512
// ---------------------------------------------------------------------------
__global__ __launch_bounds__(512, 2) void gemm1_8p_k(
    const unsigned short* __restrict__ Qt, const unsigned short* __restrict__ Kt,
    const float* __restrict__ mask, unsigned short* __restrict__ t0,
    unsigned short* __restrict__ t1, unsigned short* __restrict__ t2,
    unsigned short* __restrict__ t3, float* __restrict__ rowsum) {
  __shared__ unsigned short sA[32768];
  __shared__ unsigned short sB[32768];
  int flat = blockIdx.x + (blockIdx.y << 4) + (blockIdx.z << 8);
  int swz = (flat & 7) * 128 + (flat >> 3);
  int bx = swz & 15, by = (swz >> 4) & 15, b = swz >> 8;
  unsigned short* tbb = (b == 0) ? t0 : (b == 1) ? t1 : (b == 2) ? t2 : t3;
  int i0 = by * 256, j0 = bx * 256;
  f32x4 acc[8][4] = {};
  gemm_8phase(Qt + (size_t)b * L_ * C_ + (size_t)i0 * C_,
              Kt + (size_t)b * L_ * C_ + (size_t)j0 * C_, C_, C_, C_, sA, sB,
              acc);
  int t = threadIdx.x;
  int lane = t & 63;
  int quad = lane >> 4;
  int l15 = lane & 15;
  int w = t >> 6;
  int wm = (w & 1) * 128;
  int wn = (w >> 1) * 64;
  const float scale = 0.04419417382415922f;  // 1/sqrt(512)
  float lm[4], mv[4];
#pragma unroll
  for (int n = 0; n < 4; ++n) {
    int j = j0 + wn + n * 16 + l15;
    float m = mask[(size_t)b * L_ + j];
    mv[n] = m;
    lm[n] = __logf(m + 1e-6f);
  }
  float rs[8][4];
#pragma unroll
  for (int m = 0; m < 8; ++m)
#pragma unroll
    for (int r = 0; r < 4; ++r) rs[m][r] = 0.f;
#pragma unroll
  for (int m = 0; m < 8; ++m) {
    int irow = i0 + wm + m * 16 + quad * 4;  // C/D: row = quad*4 + reg
#pragma unroll
    for (int r = 0; r < 4; ++r) {
      size_t ro = (size_t)(irow + r) * L_;
#pragma unroll
      for (int n = 0; n < 4; ++n) {
        float x = fminf(acc[m][n][r] * scale + lm[n], 60.f);
        float tv = __expf(x);  // |logit| small: max-free softmax is safe
        rs[m][r] += tv;
        tbb[ro + j0 + wn + n * 16 + l15] = f2bf_rne(tv * mv[n]);
      }
    }
  }
#pragma unroll
  for (int mm = 1; mm < 16; mm <<= 1)
#pragma unroll
    for (int m = 0; m < 8; ++m)
#pragma unroll
      for (int r = 0; r < 4; ++r) rs[m][r] += __shfl_xor(rs[m][r], mm, 64);
  if (l15 == 0) {
    float* rb = rowsum + (size_t)b * L_ + i0 + wm;
#pragma unroll
    for (int m = 0; m < 8; ++m)
#pragma unroll
      for (int r = 0; r < 4; ++r)
        atomicAdd(&rb[m * 16 + quad * 4 + r], rs[m][r]);
  }
}

// ===========================================================================
// 128x128 2-phase NT GEMM mainloop, BK=64 (round-2, verified).
// ===========================================================================
__device__ __forceinline__ void gemm_mainloop64(
    const unsigned short* Ab, const unsigned short* Bb, int lda, int ldb,
    int Kdim, unsigned short* sA, unsigned short* sB, f32x4 acc[4][4]) {
  int t = threadIdx.x;
  const unsigned short* pA[4];
  const unsigned short* pB[4];
#pragma unroll
  for (int c = 0; c < 4; ++c) {
    int e = t * 8 + c * 2048;
    int kc = e >> 12;
    int rem = e & 4095;
    int row = rem >> 5;
    int col = rem & 31;
    int off = kc * 32 + col;
    pA[c] = Ab + (size_t)row * lda + off;
    pB[c] = Bb + (size_t)row * ldb + off;
  }
  int lane = t & 63;
  int quad = lane >> 4;
  int l15 = lane & 15;
  int w = t >> 6;
  int wm = (w & 1) * 64;
  int wn = (w >> 1) * 64;
  for (int kk = 0; kk < Kdim; kk += 64) {
    __syncthreads();
#pragma unroll
    for (int c = 0; c < 4; ++c) g2lds16(pA[c] + kk, sA + t * 8 + c * 2048);
#pragma unroll
    for (int c = 0; c < 4; ++c) g2lds16(pB[c] + kk, sB + t * 8 + c * 2048);
    __syncthreads();
#pragma unroll
    for (int kc = 0; kc < 2; ++kc) {
      bf16x8 aF[4], bF[4];
#pragma unroll
      for (int ti = 0; ti < 4; ++ti)
        aF[ti] = *(const bf16x8*)(sA + kc * 4096 +
                                  (wm + ti * 16 + l15) * 32 + quad * 8);
#pragma unroll
      for (int tj = 0; tj < 4; ++tj)
        bF[tj] = *(const bf16x8*)(sB + kc * 4096 +
                                  (wn + tj * 16 + l15) * 32 + quad * 8);
#pragma unroll
      for (int ti = 0; ti < 4; ++ti)
#pragma unroll
        for (int tj = 0; tj < 4; ++tj)
          acc[ti][tj] = MFMA16(aF[ti], bF[tj], acc[ti][tj]);
    }
  }
}

// ---------------------------------------------------------------------------
// K2+K3 merged (fast path): block-uniform branch.
//  fb < 1024:  gemm2 (128x128, split-K=2): out[c,i] = inv[i]*sum_j Vb*tb;
//              ks=0 -> out, ks=1 -> out2 (combined by combine_out_k after).
//  fb >= 1024: finalize: attn[b][j,i] = bf2f(tb[b][i,j]) / rowsum[b][i].
// The finalize half depends only on gemm1 (tb, rowsum), NOT on gemm2 -> the
// two halves are independent and co-resident (32 KB LDS, 256 thr -> 5/CU):
// finalize's BW-bound blocks soak HBM while gemm2's MFMA blocks compute.
// grid (1024 + 16384) 1-D, block 256.
// ---------------------------------------------------------------------------
__global__ __launch_bounds__(256) void gemm2_fin_k(
    const unsigned short* __restrict__ Vb, const unsigned short* __restrict__ t0,
    const unsigned short* __restrict__ t1, const unsigned short* __restrict__ t2,
    const unsigned short* __restrict__ t3, const float* __restrict__ rowsum,
    float* __restrict__ out, float* __restrict__ out2,
    float* __restrict__ attn) {
  __shared__ __align__(16) unsigned char smem[32768];
  int fb = blockIdx.x;
  int t = threadIdx.x;
  if (fb < 1024) {
    unsigned short* sA = (unsigned short*)smem;
    unsigned short* sB = (unsigned short*)(smem + 16384);
    int ix = fb & 31, cy = (fb >> 5) & 3, z = fb >> 7;
    int b = z & 3, ks = z >> 2;
    const unsigned short* tbb =
        (b == 0) ? t0 : (b == 1) ? t1 : (b == 2) ? t2 : t3;
    int i0 = ix * 128, c0 = cy * 128;
    f32x4 acc[4][4] = {};
    gemm_mainloop64(Vb + (size_t)b * C_ * L_ + (size_t)c0 * L_ + ks * (L_ / 2),
                    tbb + (size_t)i0 * L_ + ks * (L_ / 2), L_, L_, L_ / 2, sA,
                    sB, acc);
    int lane = t & 63;
    int quad = lane >> 4;
    int l15 = lane & 15;
    int w = t >> 6;
    int wm = (w & 1) * 64;
    int wn = (w >> 1) * 64;
    float invv[4];
#pragma unroll
    for (int tj = 0; tj < 4; ++tj)
      invv[tj] = 1.0f / rowsum[(size_t)b * L_ + i0 + wn + tj * 16 + l15];
    float* ob = (ks ? out2 : out) + (size_t)b * C_ * L_;
#pragma unroll
    for (int ti = 0; ti < 4; ++ti) {
      int crow = c0 + wm + ti * 16 + quad * 4;
#pragma unroll
      for (int r = 0; r < 4; ++r) {
        size_t ro = (size_t)(crow + r) * L_;
#pragma unroll
        for (int tj = 0; tj < 4; ++tj)
          ob[ro + i0 + wn + tj * 16 + l15] = acc[ti][tj][r] * invv[tj];
      }
    }
  } else {
    float(*tileT)[65] = (float(*)[65])smem;
    int g = fb - 1024;
    int jt = g & 63, it = (g >> 6) & 63, b = g >> 12;
    const unsigned short* src = t0 + (size_t)b * L_ * L_;  // t0==tb base
    const float* rs = rowsum + (size_t)b * L_;
    float* dst = attn + (size_t)b * L_ * L_;
    int r = t >> 2, cg = (t & 3) * 16;
    int i = it * 64 + r;
    float inv = 1.0f / rs[i];
    const unsigned short* sp = src + (size_t)i * L_ + jt * 64 + cg;
    uint4 u0 = *(const uint4*)sp;
    uint4 u1 = *(const uint4*)(sp + 8);
    const unsigned* w0 = (const unsigned*)&u0;
    const unsigned* w1 = (const unsigned*)&u1;
#pragma unroll
    for (int k = 0; k < 4; ++k) {
      tileT[cg + 2 * k + 0][r] = bflo2f(w0[k]) * inv;
      tileT[cg + 2 * k + 1][r] = bfhi2f(w0[k]) * inv;
      tileT[cg + 8 + 2 * k + 0][r] = bflo2f(w1[k]) * inv;
      tileT[cg + 8 + 2 * k + 1][r] = bfhi2f(w1[k]) * inv;
    }
    __syncthreads();
    float* dp = dst + (size_t)(jt * 64 + r) * L_ + it * 64 + cg;
#pragma unroll
    for (int q = 0; q < 4; ++q) {
      float4 o;
      o.x = tileT[r][cg + 4 * q + 0];
      o.y = tileT[r][cg + 4 * q + 1];
      o.z = tileT[r][cg + 4 * q + 2];
      o.w = tileT[r][cg + 4 * q + 3];
      *(float4*)(dp + 4 * q) = o;
    }
  }
}

// ---------------------------------------------------------------------------
// K4: out += out2  (split-K combine).  grid (B*C*L)/2048, block 256.
// ---------------------------------------------------------------------------
__global__ __launch_bounds__(256) void combine_out_k(
    float* __restrict__ out, const float* __restrict__ out2) {
  size_t idx = ((size_t)blockIdx.x * 256 + threadIdx.x) * 8;
  float4 a0 = *(const float4*)(out + idx);
  float4 a1 = *(const float4*)(out + idx + 4);
  float4 b0 = *(const float4*)(out2 + idx);
  float4 b1 = *(const float4*)(out2 + idx + 4);
  a0.x += b0.x; a0.y += b0.y; a0.z += b0.z; a0.w += b0.w;
  a1.x += b1.x; a1.y += b1.y; a1.z += b1.z; a1.w += b1.w;
  *(float4*)(out + idx) = a0;
  *(float4*)(out + idx + 4) = a1;
}

// ---------------------------------------------------------------------------
// K3 standalone (fallback tier): attn[b][j,i] = bf2f(tb[b][i,j]) / rowsum[i].
// grid (64, 64, 1), block 256.
// ---------------------------------------------------------------------------
__global__ __launch_bounds__(256) void finalize_one_k(
    const unsigned short* __restrict__ tb, const float* __restrict__ rowsum,
    float* __restrict__ attn) {
  int t = threadIdx.x;
  const unsigned short* src = tb;
  const float* rs = rowsum;
  float* dst = attn;
  int jt = blockIdx.x, it = blockIdx.y;
  __shared__ float tileT[64][65];
  int r = t >> 2, cg = (t & 3) * 16;
  int i = it * 64 + r;
  float inv = 1.0f / rs[i];
  const unsigned short* sp = src + (size_t)i * L_ + jt * 64 + cg;
  uint4 u0 = *(const uint4*)sp;
  uint4 u1 = *(const uint4*)(sp + 8);
  const unsigned* w0 = (const unsigned*)&u0;
  const unsigned* w1 = (const unsigned*)&u1;
#pragma unroll
  for (int k = 0; k < 4; ++k) {
    tileT[cg + 2 * k + 0][r] = bflo2f(w0[k]) * inv;
    tileT[cg + 2 * k + 1][r] = bfhi2f(w0[k]) * inv;
    tileT[cg + 8 + 2 * k + 0][r] = bflo2f(w1[k]) * inv;
    tileT[cg + 8 + 2 * k + 1][r] = bfhi2f(w1[k]) * inv;
  }
  __syncthreads();
  float* dp = dst + (size_t)(jt * 64 + r) * L_ + it * 64 + cg;
#pragma unroll
  for (int q = 0; q < 4; ++q) {
    float4 o;
    o.x = tileT[r][cg + 4 * q + 0];
    o.y = tileT[r][cg + 4 * q + 1];
    o.z = tileT[r][cg + 4 * q + 2];
    o.w = tileT[r][cg + 4 * q + 3];
    *(float4*)(dp + 4 * q) = o;
  }
}

// ===========================================================================
// FALLBACK tier kernels (small ws): round-2 proven 128x128 2-phase pipeline.
// ===========================================================================
__global__ __launch_bounds__(256) void gemm1_bf_k(
    const unsigned short* __restrict__ Qt, const unsigned short* __restrict__ Kt,
    const float* __restrict__ mask, unsigned short* __restrict__ t0,
    unsigned short* __restrict__ t1, unsigned short* __restrict__ t2,
    unsigned short* __restrict__ t3, float* __restrict__ rowsum) {
  int b = blockIdx.z;
  unsigned short* tbb = (b == 0) ? t0 : (b == 1) ? t1 : (b == 2) ? t2 : t3;
  int i0 = blockIdx.y * 128;
  int j0 = blockIdx.x * 128;
  __shared__ unsigned short sA[8192];
  __shared__ unsigned short sB[8192];
  f32x4 acc[4][4] = {};
  gemm_mainloop64(Qt + (size_t)b * L_ * C_ + (size_t)i0 * C_,
                  Kt + (size_t)b * L_ * C_ + (size_t)j0 * C_, C_, C_, C_, sA,
                  sB, acc);
  int t = threadIdx.x;
  int lane = t & 63;
  int quad = lane >> 4;
  int l15 = lane & 15;
  int w = t >> 6;
  int wm = (w & 1) * 64;
  int wn = (w >> 1) * 64;
  const float scale = 0.04419417382415922f;
  float lm[4], mv[4];
#pragma unroll
  for (int tj = 0; tj < 4; ++tj) {
    int j = j0 + wn + tj * 16 + l15;
    float m = mask[(size_t)b * L_ + j];
    mv[tj] = m;
    lm[tj] = __logf(m + 1e-6f);
  }
  float rs[16];
#pragma unroll
  for (int q = 0; q < 16; ++q) rs[q] = 0.f;
#pragma unroll
  for (int ti = 0; ti < 4; ++ti) {
    int irow = i0 + wm + ti * 16 + quad * 4;
#pragma unroll
    for (int r = 0; r < 4; ++r) {
      size_t ro = (size_t)(irow + r) * L_;
#pragma unroll
      for (int tj = 0; tj < 4; ++tj) {
        float x = fminf(acc[ti][tj][r] * scale + lm[tj], 60.f);
        float tv = __expf(x);
        rs[ti * 4 + r] += tv;
        tbb[ro + j0 + wn + tj * 16 + l15] = f2bf_rne(tv * mv[tj]);
      }
    }
  }
#pragma unroll
  for (int m = 1; m < 16; m <<= 1)
#pragma unroll
    for (int q = 0; q < 16; ++q) rs[q] += __shfl_xor(rs[q], m, 64);
  if (l15 == 0) {
    float* rb = rowsum + (size_t)b * L_ + i0 + wm;
#pragma unroll
    for (int ti = 0; ti < 4; ++ti)
#pragma unroll
      for (int r = 0; r < 4; ++r)
        atomicAdd(&rb[ti * 16 + quad * 4 + r], rs[ti * 4 + r]);
  }
}

__global__ __launch_bounds__(256) void gemm2_bf_k(
    const unsigned short* __restrict__ Vb, const unsigned short* __restrict__ t0,
    const unsigned short* __restrict__ t1, const unsigned short* __restrict__ t2,
    const unsigned short* __restrict__ t3, const float* __restrict__ rowsum,
    float* __restrict__ out) {
  int z = blockIdx.z;
  int b = z & 3;
  int ks = z >> 2;
  const unsigned short* tbb =
      (b == 0) ? t0 : (b == 1) ? t1 : (b == 2) ? t2 : t3;
  int c0 = blockIdx.y * 128;
  int i0 = blockIdx.x * 128;
  __shared__ unsigned short sA[8192];
  __shared__ unsigned short sB[8192];
  f32x4 acc[4][4] = {};
  gemm_mainloop64(Vb + (size_t)b * C_ * L_ + (size_t)c0 * L_ + ks * (L_ / 2),
                  tbb + (size_t)i0 * L_ + ks * (L_ / 2), L_, L_, L_ / 2, sA, sB,
                  acc);
  int t = threadIdx.x;
  int lane = t & 63;
  int quad = lane >> 4;
  int l15 = lane & 15;
  int w = t >> 6;
  int wm = (w & 1) * 64;
  int wn = (w >> 1) * 64;
  float invv[4];
#pragma unroll
  for (int tj = 0; tj < 4; ++tj)
    invv[tj] = 1.0f / rowsum[(size_t)b * L_ + i0 + wn + tj * 16 + l15];
  float* ob = out + (size_t)b * C_ * L_;
#pragma unroll
  for (int ti = 0; ti < 4; ++ti) {
    int crow = c0 + wm + ti * 16 + quad * 4;
#pragma unroll
    for (int r = 0; r < 4; ++r) {
      size_t ro = (size_t)(crow + r) * L_;
#pragma unroll
      for (int tj = 0; tj < 4; ++tj)
        atomicAdd(&ob[ro + i0 + wn + tj * 16 + l15],
                  acc[ti][tj][r] * invv[tj]);
    }
  }
}

extern "C" void kernel_launch(void* const* d_in, const int* in_sizes, int n_in,
                              void* d_out, int out_size, void* d_ws,
                              size_t ws_size, hipStream_t stream) {
  const float* Q = (const float*)d_in[0];
  const float* K = (const float*)d_in[1];
  const float* V = (const float*)d_in[2];
  const float* mask = (const float*)d_in[3];

  float* out = (float*)d_out;                // (B,C,L) fp32
  float* attn = out + (size_t)B_ * C_ * L_;  // (B,L,L) fp32

  const size_t NQ = (size_t)B_ * L_ * C_;    // elems per bf16 operand tensor
  const size_t SLOT = (size_t)L_ * L_;       // elems per (L,L) matrix
  unsigned short* Qt = (unsigned short*)d_ws;
  unsigned short* Kt = Qt + NQ;
  unsigned short* Vb = Kt + NQ;
  float* rowsum = (float*)(Vb + NQ);
  unsigned short* wtail = (unsigned short*)(rowsum + (size_t)B_ * L_);

  // tier-1: tb (B,L,L) bf16 + out2 (B,C,L) fp32 in dedicated workspace
  const size_t need1 =
      NQ * 2 * 3 + (size_t)B_ * L_ * 4 + (size_t)B_ * SLOT * 2 + NQ * 4;

  prep_k<<<dim3(64, 8, 12), 256, 0, stream>>>(Q, K, V, mask, Qt, Kt, Vb,
                                              rowsum);

  if (ws_size >= need1) {
    unsigned short* tb = wtail;                      // (B,L,L) bf16
    float* out2 = (float*)(tb + (size_t)B_ * SLOT);  // (B,C,L) fp32
    gemm1_8p_k<<<dim3(16, 16, B_), 512, 0, stream>>>(
        Qt, Kt, mask, tb, tb + SLOT, tb + 2 * SLOT, tb + 3 * SLOT, rowsum);
    // merged gemm2 + finalize (independent halves; finalize needs only gemm1)
    gemm2_fin_k<<<dim3(1024 + 16384), 256, 0, stream>>>(
        Vb, tb, tb + SLOT, tb + 2 * SLOT, tb + 3 * SLOT, rowsum, out, out2,
        attn);
    combine_out_k<<<dim3((B_ * C_ * L_) / 2048), 256, 0, stream>>>(out, out2);
  } else {
    // fallback tier: tb parked in not-yet-final attn slots (round-1 layout).
    unsigned short* tb0 = (unsigned short*)(attn + 2 * SLOT);
    unsigned short* tb1 = (unsigned short*)(attn + 3 * SLOT);
    unsigned short* tb2 = (unsigned short*)(attn + 3 * SLOT + SLOT / 2);
    unsigned short* tb3 = wtail;
    hipMemsetAsync(out, 0, (size_t)B_ * C_ * L_ * sizeof(float), stream);
    gemm1_bf_k<<<dim3(L_ / 128, L_ / 128, B_), 256, 0, stream>>>(
        Qt, Kt, mask, tb0, tb1, tb2, tb3, rowsum);
    gemm2_bf_k<<<dim3(L_ / 128, C_ / 128, B_ * 2), 256, 0, stream>>>(
        Vb, tb0, tb1, tb2, tb3, rowsum, out);
    finalize_one_k<<<dim3(64, 64, 1), 256, 0, stream>>>(tb0, rowsum, attn);
    finalize_one_k<<<dim3(64, 64, 1), 256, 0, stream>>>(tb1, rowsum + L_,
                                                        attn + SLOT);
    finalize_one_k<<<dim3(64, 64, 1), 256, 0, stream>>>(tb2, rowsum + 2 * L_,
                                                        attn + 2 * SLOT);
    finalize_one_k<<<dim3(64, 64, 1), 256, 0, stream>>>(tb3, rowsum + 3 * L_,
                                                        attn + 3 * SLOT);
  }
}

// Round 10
// 649.746 us; speedup vs baseline: 1.0439x; 1.0439x over previous
//
#include <hip/hip_runtime.h>

#define B_ 4
#define C_ 512
#define L_ 4096

typedef __attribute__((ext_vector_type(8))) short bf16x8;
typedef __attribute__((ext_vector_type(4))) float f32x4;

#define MFMA16(a, b, c) __builtin_amdgcn_mfma_f32_16x16x32_bf16(a, b, c, 0, 0, 0)

static __device__ __forceinline__ unsigned short f2bf_rne(float f) {
  unsigned u = __float_as_uint(f);
  u += 0x7FFFu + ((u >> 16) & 1u);  // round-to-nearest-even
  return (unsigned short)(u >> 16);
}
static __device__ __forceinline__ unsigned pack_rne(float a, float b) {
  return (unsigned)f2bf_rne(a) | ((unsigned)f2bf_rne(b) << 16);
}
static __device__ __forceinline__ float bflo2f(unsigned w) {
  return __uint_as_float(w << 16);
}
static __device__ __forceinline__ float bfhi2f(unsigned w) {
  return __uint_as_float(w & 0xFFFF0000u);
}

// async global -> LDS, 16 B/lane; LDS dest = wave-uniform base + lane*16.
static __device__ __forceinline__ void g2lds16(const unsigned short* g,
                                               unsigned short* l) {
  __builtin_amdgcn_global_load_lds(
      (const __attribute__((address_space(1))) unsigned int*)g,
      (__attribute__((address_space(3))) unsigned int*)l, 16, 0, 0);
}

#define BAR_() __builtin_amdgcn_s_barrier()
#define LGKM0_() asm volatile("s_waitcnt lgkmcnt(0)" ::: "memory")
#define VMW_(N) asm volatile("s_waitcnt vmcnt(" #N ")" ::: "memory")

// ---------------------------------------------------------------------------
// K0 (fused): z<8:  Q,K fp32 (C,L) -> Qt,Kt bf16 (L,C)   (64x64 LDS transpose)
//             z>=8: Vb[b,c,j] = bf16(V[b,c,j]*mask[b,j]) (streaming cast)
//             block (0,0,8) additionally zeroes rowsum (16384 floats).
// grid (64, 8, 12), block 256.  Branch is block-uniform.
// ---------------------------------------------------------------------------
__global__ __launch_bounds__(256) void prep_k(
    const float* __restrict__ Q, const float* __restrict__ K,
    const float* __restrict__ V, const float* __restrict__ mask,
    unsigned short* __restrict__ Qt, unsigned short* __restrict__ Kt,
    unsigned short* __restrict__ Vb, float* __restrict__ rowsum) {
  int zb = blockIdx.z;
  int t = threadIdx.x;
  __shared__ float tile[64][65];
  if (zb < 8) {
    int b = zb >> 1;
    const float* src = ((zb & 1) ? K : Q) + (size_t)b * C_ * L_;
    unsigned short* dst = ((zb & 1) ? Kt : Qt) + (size_t)b * L_ * C_;
    int i0 = blockIdx.x * 64, c0 = blockIdx.y * 64;
    int cr = t >> 2, ig = (t & 3) * 16;
    const float* s = src + (size_t)(c0 + cr) * L_ + i0 + ig;
#pragma unroll
    for (int q = 0; q < 4; ++q) {
      float4 v = *(const float4*)(s + 4 * q);
      tile[cr][ig + 4 * q + 0] = v.x;
      tile[cr][ig + 4 * q + 1] = v.y;
      tile[cr][ig + 4 * q + 2] = v.z;
      tile[cr][ig + 4 * q + 3] = v.w;
    }
    __syncthreads();
    int ir = t >> 2, cg = (t & 3) * 16;
    unsigned wds[8];
#pragma unroll
    for (int k = 0; k < 8; ++k)
      wds[k] = pack_rne(tile[cg + 2 * k][ir], tile[cg + 2 * k + 1][ir]);
    unsigned short* d = dst + (size_t)(i0 + ir) * C_ + c0 + cg;
    uint4 o0, o1;
    o0.x = wds[0]; o0.y = wds[1]; o0.z = wds[2]; o0.w = wds[3];
    o1.x = wds[4]; o1.y = wds[5]; o1.z = wds[6]; o1.w = wds[7];
    *(uint4*)d = o0;
    *(uint4*)(d + 8) = o1;
  } else {
    int b = zb - 8;
    int flat = blockIdx.x + (blockIdx.y << 6);  // 0..511
    if (b == 0 && flat == 0) {                  // zero rowsum (B_*L_ floats)
      float4 z4 = {0.f, 0.f, 0.f, 0.f};
#pragma unroll
      for (int q = 0; q < 16; ++q)
        *(float4*)(rowsum + (q * 256 + t) * 4) = z4;
    }
    size_t base = (size_t)b * C_ * L_ + (size_t)flat * 4096 + (size_t)t * 16;
    int j = (int)(base & (L_ - 1));  // 16-elem group stays within one row
    const float* vp = V + base;
    const float* mp = mask + (size_t)b * L_ + j;
#pragma unroll
    for (int g = 0; g < 2; ++g) {
      float4 v0 = *(const float4*)(vp + g * 8);
      float4 v1 = *(const float4*)(vp + g * 8 + 4);
      float4 m0 = *(const float4*)(mp + g * 8);
      float4 m1 = *(const float4*)(mp + g * 8 + 4);
      uint4 o;
      o.x = pack_rne(v0.x * m0.x, v0.y * m0.y);
      o.y = pack_rne(v0.z * m0.z, v0.w * m0.w);
      o.z = pack_rne(v1.x * m1.x, v1.y * m1.y);
      o.w = pack_rne(v1.z * m1.z, v1.w * m1.w);
      *(uint4*)(Vb + base + g * 8) = o;
    }
  }
}

// ===========================================================================
// 256x256 8-phase NT GEMM mainloop (round-3, verified).
// ===========================================================================
__device__ __forceinline__ void gemm_8phase(
    const unsigned short* __restrict__ Ab,
    const unsigned short* __restrict__ Bb, int lda, int ldb, int Kdim,
    unsigned short* sA, unsigned short* sB, f32x4 (&acc)[8][4]) {
  const int t = threadIdx.x;
  const int lane = t & 63;
  const int quad = lane >> 4;
  const int l15 = lane & 15;
  const int w = t >> 6;
  const int wm = (w & 1) * 128;
  const int wn = (w >> 1) * 64;
  const int et = (t * 8) ^ (((t >> 5) & 1) << 4);
  const int srw = et >> 5;
  const int scl = et & 31;
  const int nt = Kdim >> 6;

  auto stage = [&](int nom, int hh) {
    int st = nom < nt ? nom : nt - 1;
    int db = nom & 1;
    int h = hh & 1;
    const unsigned short* g;
    unsigned short* l;
    if (hh < 2) {
      g = Bb + (size_t)(h * 128 + srw) * ldb + st * 64 + scl;
      l = sB + db * 16384 + h * 4096 + t * 8;
    } else {
      g = Ab + (size_t)(h * 128 + srw) * lda + st * 64 + scl;
      l = sA + db * 16384 + h * 4096 + t * 8;
    }
    g2lds16(g, l);
    g2lds16(g + 32, l + 8192);
  };
  auto rd = [&](const unsigned short* s, int db, int kc, int row) -> bf16x8 {
    int e = db * 16384 + kc * 8192 + row * 32 + quad * 8;
    e ^= ((e >> 8) & 1) << 4;
    return *(const bf16x8*)(s + e);
  };

  bf16x8 aF[4][2], b0[2][2], b1[2][2];
  auto rdA4 = [&](int db, int mbase) {
#pragma unroll
    for (int m = 0; m < 4; ++m)
#pragma unroll
      for (int kc = 0; kc < 2; ++kc)
        aF[m][kc] = rd(sA, db, kc, wm + (mbase + m) * 16 + l15);
  };
  auto rdB2 = [&](bf16x8 (&bf)[2][2], int db, int nbase) {
#pragma unroll
    for (int n = 0; n < 2; ++n)
#pragma unroll
      for (int kc = 0; kc < 2; ++kc)
        bf[n][kc] = rd(sB, db, kc, wn + (nbase + n) * 16 + l15);
  };
  auto mfma8 = [&](bf16x8 (&bf)[2][2], int mo, int no) {
    __builtin_amdgcn_s_setprio(1);
#pragma unroll
    for (int m = 0; m < 4; ++m)
#pragma unroll
      for (int n = 0; n < 2; ++n) {
        acc[mo + m][no + n] = MFMA16(aF[m][0], bf[n][0], acc[mo + m][no + n]);
        acc[mo + m][no + n] = MFMA16(aF[m][1], bf[n][1], acc[mo + m][no + n]);
      }
    __builtin_amdgcn_s_setprio(0);
  };

  stage(0, 0); stage(0, 1); stage(0, 2); stage(0, 3);
  asm volatile("s_waitcnt vmcnt(4)" ::: "memory");
  stage(1, 0); stage(1, 1); stage(1, 2);
  asm volatile("s_waitcnt vmcnt(6)" ::: "memory");
  BAR_();

  const int ni = nt >> 1;
  for (int i = 0; i < ni; ++i) {
    const int X = 2 * i;
    rdA4(0, 0); rdB2(b0, 0, 0); rdB2(b1, 0, 2);
    stage(X + 1, 3);
    BAR_(); LGKM0_();
    mfma8(b0, 0, 0);
    BAR_();
    stage(X + 2, 0);
    BAR_();
    mfma8(b1, 0, 2);
    BAR_();
    rdA4(0, 4);
    stage(X + 2, 1);
    BAR_(); LGKM0_();
    mfma8(b0, 4, 0);
    BAR_();
    stage(X + 2, 2);
    VMW_(6); BAR_();
    mfma8(b1, 4, 2);
    BAR_(); __builtin_amdgcn_sched_barrier(0);
    rdA4(1, 0); rdB2(b0, 1, 0); rdB2(b1, 1, 2);
    stage(X + 2, 3);
    BAR_(); LGKM0_();
    mfma8(b0, 0, 0);
    BAR_();
    stage(X + 3, 0);
    BAR_();
    mfma8(b1, 0, 2);
    BAR_();
    rdA4(1, 4);
    stage(X + 3, 1);
    BAR_(); LGKM0_();
    mfma8(b0, 4, 0);
    BAR_();
    stage(X + 3, 2);
    VMW_(6); BAR_();
    mfma8(b1, 4, 2);
    BAR_(); __builtin_amdgcn_sched_barrier(0);
  }
  asm volatile("s_waitcnt vmcnt(0)" ::: "memory");
}

// ---------------------------------------------------------------------------
// K1 (8-phase): E = Qt*Kt^T; tv = exp(E*scale + log(mask+1e-6));
// tb = bf16(tv*mask); fp32 rowsum atomics.  grid (16,16,4), block 512
// ---------------------------------------------------------------------------
__global__ __launch_bounds__(512, 2) void gemm1_8p_k(
    const unsigned short* __restrict__ Qt, const unsigned short* __restrict__ Kt,
    const float* __restrict__ mask, unsigned short* __restrict__ t0,
    unsigned short* __restrict__ t1, unsigned short* __restrict__ t2,
    unsigned short* __restrict__ t3, float* __restrict__ rowsum) {
  __shared__ unsigned short sA[32768];
  __shared__ unsigned short sB[32768];
  int flat = blockIdx.x + (blockIdx.y << 4) + (blockIdx.z << 8);
  int swz = (flat & 7) * 128 + (flat >> 3);
  int bx = swz & 15, by = (swz >> 4) & 15, b = swz >> 8;
  unsigned short* tbb = (b == 0) ? t0 : (b == 1) ? t1 : (b == 2) ? t2 : t3;
  int i0 = by * 256, j0 = bx * 256;
  f32x4 acc[8][4] = {};
  gemm_8phase(Qt + (size_t)b * L_ * C_ + (size_t)i0 * C_,
              Kt + (size_t)b * L_ * C_ + (size_t)j0 * C_, C_, C_, C_, sA, sB,
              acc);
  int t = threadIdx.x;
  int lane = t & 63;
  int quad = lane >> 4;
  int l15 = lane & 15;
  int w = t >> 6;
  int wm = (w & 1) * 128;
  int wn = (w >> 1) * 64;
  const float scale = 0.04419417382415922f;  // 1/sqrt(512)
  float lm[4], mv[4];
#pragma unroll
  for (int n = 0; n < 4; ++n) {
    int j = j0 + wn + n * 16 + l15;
    float m = mask[(size_t)b * L_ + j];
    mv[n] = m;
    lm[n] = __logf(m + 1e-6f);
  }
  float rs[8][4];
#pragma unroll
  for (int m = 0; m < 8; ++m)
#pragma unroll
    for (int r = 0; r < 4; ++r) rs[m][r] = 0.f;
#pragma unroll
  for (int m = 0; m < 8; ++m) {
    int irow = i0 + wm + m * 16 + quad * 4;  // C/D: row = quad*4 + reg
#pragma unroll
    for (int r = 0; r < 4; ++r) {
      size_t ro = (size_t)(irow + r) * L_;
#pragma unroll
      for (int n = 0; n < 4; ++n) {
        float x = fminf(acc[m][n][r] * scale + lm[n], 60.f);
        float tv = __expf(x);  // |logit| small: max-free softmax is safe
        rs[m][r] += tv;
        tbb[ro + j0 + wn + n * 16 + l15] = f2bf_rne(tv * mv[n]);
      }
    }
  }
#pragma unroll
  for (int mm = 1; mm < 16; mm <<= 1)
#pragma unroll
    for (int m = 0; m < 8; ++m)
#pragma unroll
      for (int r = 0; r < 4; ++r) rs[m][r] += __shfl_xor(rs[m][r], mm, 64);
  if (l15 == 0) {
    float* rb = rowsum + (size_t)b * L_ + i0 + wm;
#pragma unroll
    for (int m = 0; m < 8; ++m)
#pragma unroll
      for (int r = 0; r < 4; ++r)
        atomicAdd(&rb[m * 16 + quad * 4 + r], rs[m][r]);
  }
}

// ---------------------------------------------------------------------------
// K2 (8-phase): out[c,i] = inv[i]*sum_j Vb[c,j]*tb[i,j].  split-K=2 over j;
// ks=0 -> out, ks=1 -> out2 (combined in finalize).  grid (16,2,8), block 512
// ---------------------------------------------------------------------------
__global__ __launch_bounds__(512, 2) void gemm2_8p_k(
    const unsigned short* __restrict__ Vb, const unsigned short* __restrict__ t0,
    const unsigned short* __restrict__ t1, const unsigned short* __restrict__ t2,
    const unsigned short* __restrict__ t3, const float* __restrict__ rowsum,
    float* __restrict__ out, float* __restrict__ out2) {
  __shared__ unsigned short sA[32768];
  __shared__ unsigned short sB[32768];
  // bijective XCD swizzle (nwg=256): logical group z == physical XCD,
  // so the 16 i-tiles sharing a Vb panel and the cy pair sharing tb rows
  // are co-resident on one XCD's L2.
  int flat = blockIdx.x + (blockIdx.y << 4) + (blockIdx.z << 5);
  int swz = (flat & 7) * 32 + (flat >> 3);
  int ix = swz & 15, cy = (swz >> 4) & 1, z = swz >> 5;
  int b = z & 3, ks = z >> 2;
  const unsigned short* tbb =
      (b == 0) ? t0 : (b == 1) ? t1 : (b == 2) ? t2 : t3;
  int i0 = ix * 256, c0 = cy * 256;
  f32x4 acc[8][4] = {};
  gemm_8phase(Vb + (size_t)b * C_ * L_ + (size_t)c0 * L_ + ks * (L_ / 2),
              tbb + (size_t)i0 * L_ + ks * (L_ / 2), L_, L_, L_ / 2, sA, sB,
              acc);
  int t = threadIdx.x;
  int lane = t & 63;
  int quad = lane >> 4;
  int l15 = lane & 15;
  int w = t >> 6;
  int wm = (w & 1) * 128;
  int wn = (w >> 1) * 64;
  float invv[4];
#pragma unroll
  for (int n = 0; n < 4; ++n)
    invv[n] = 1.0f / rowsum[(size_t)b * L_ + i0 + wn + n * 16 + l15];
  float* ob = (ks ? out2 : out) + (size_t)b * C_ * L_;
#pragma unroll
  for (int m = 0; m < 8; ++m) {
    int crow = c0 + wm + m * 16 + quad * 4;
#pragma unroll
    for (int r = 0; r < 4; ++r) {
      size_t ro = (size_t)(crow + r) * L_;
#pragma unroll
      for (int n = 0; n < 4; ++n)
        ob[ro + i0 + wn + n * 16 + l15] = acc[m][n][r] * invv[n];
    }
  }
}

// ---------------------------------------------------------------------------
// K3: attn[b][j,i] = bf2f(tb[b][i,j]) / rowsum[b][i]   (out-of-place), plus
// (fast path) folded split-K combine: blocks with flat<8192 also do
// out[chunk] += out2[chunk] (1024 floats each; 8192*1024 = B*C*L).
// grid (64, 64, nb), block 256.  For nb>1, tb/attn must not alias.
// ---------------------------------------------------------------------------
__global__ __launch_bounds__(256) void finalize_all_k(
    const unsigned short* __restrict__ tb, const float* __restrict__ rowsum,
    float* __restrict__ attn, float* __restrict__ out,
    const float* __restrict__ out2) {
  int b = blockIdx.z;
  int t = threadIdx.x;
  if (out2 != nullptr) {
    int flat = blockIdx.x + (blockIdx.y << 6) + (blockIdx.z << 12);
    if (flat < 8192) {
      size_t idx = (size_t)flat * 1024 + (size_t)t * 4;
      float4 a = *(const float4*)(out + idx);
      float4 c = *(const float4*)(out2 + idx);
      a.x += c.x; a.y += c.y; a.z += c.z; a.w += c.w;
      *(float4*)(out + idx) = a;
    }
  }
  const unsigned short* src = tb + (size_t)b * L_ * L_;
  const float* rs = rowsum + (size_t)b * L_;
  float* dst = attn + (size_t)b * L_ * L_;
  int jt = blockIdx.x, it = blockIdx.y;
  __shared__ float tileT[64][65];
  int r = t >> 2, cg = (t & 3) * 16;
  int i = it * 64 + r;
  float inv = 1.0f / rs[i];
  const unsigned short* sp = src + (size_t)i * L_ + jt * 64 + cg;
  uint4 u0 = *(const uint4*)sp;
  uint4 u1 = *(const uint4*)(sp + 8);
  const unsigned* w0 = (const unsigned*)&u0;
  const unsigned* w1 = (const unsigned*)&u1;
#pragma unroll
  for (int k = 0; k < 4; ++k) {
    tileT[cg + 2 * k + 0][r] = bflo2f(w0[k]) * inv;
    tileT[cg + 2 * k + 1][r] = bfhi2f(w0[k]) * inv;
    tileT[cg + 8 + 2 * k + 0][r] = bflo2f(w1[k]) * inv;
    tileT[cg + 8 + 2 * k + 1][r] = bfhi2f(w1[k]) * inv;
  }
  __syncthreads();
  float* dp = dst + (size_t)(jt * 64 + r) * L_ + it * 64 + cg;
#pragma unroll
  for (int q = 0; q < 4; ++q) {
    float4 o;
    o.x = tileT[r][cg + 4 * q + 0];
    o.y = tileT[r][cg + 4 * q + 1];
    o.z = tileT[r][cg + 4 * q + 2];
    o.w = tileT[r][cg + 4 * q + 3];
    *(float4*)(dp + 4 * q) = o;
  }
}

// ===========================================================================
// FALLBACK tier (small ws): round-2 proven 128x128 2-phase pipeline.
// ===========================================================================
__device__ __forceinline__ void gemm_mainloop64(
    const unsigned short* Ab, const unsigned short* Bb, int lda, int ldb,
    int Kdim, unsigned short* sA, unsigned short* sB, f32x4 acc[4][4]) {
  int t = threadIdx.x;
  const unsigned short* pA[4];
  const unsigned short* pB[4];
#pragma unroll
  for (int c = 0; c < 4; ++c) {
    int e = t * 8 + c * 2048;
    int kc = e >> 12;
    int rem = e & 4095;
    int row = rem >> 5;
    int col = rem & 31;
    int off = kc * 32 + col;
    pA[c] = Ab + (size_t)row * lda + off;
    pB[c] = Bb + (size_t)row * ldb + off;
  }
  int lane = t & 63;
  int quad = lane >> 4;
  int l15 = lane & 15;
  int w = t >> 6;
  int wm = (w & 1) * 64;
  int wn = (w >> 1) * 64;
  for (int kk = 0; kk < Kdim; kk += 64) {
    __syncthreads();
#pragma unroll
    for (int c = 0; c < 4; ++c) g2lds16(pA[c] + kk, sA + t * 8 + c * 2048);
#pragma unroll
    for (int c = 0; c < 4; ++c) g2lds16(pB[c] + kk, sB + t * 8 + c * 2048);
    __syncthreads();
#pragma unroll
    for (int kc = 0; kc < 2; ++kc) {
      bf16x8 aF[4], bF[4];
#pragma unroll
      for (int ti = 0; ti < 4; ++ti)
        aF[ti] = *(const bf16x8*)(sA + kc * 4096 +
                                  (wm + ti * 16 + l15) * 32 + quad * 8);
#pragma unroll
      for (int tj = 0; tj < 4; ++tj)
        bF[tj] = *(const bf16x8*)(sB + kc * 4096 +
                                  (wn + tj * 16 + l15) * 32 + quad * 8);
#pragma unroll
      for (int ti = 0; ti < 4; ++ti)
#pragma unroll
        for (int tj = 0; tj < 4; ++tj)
          acc[ti][tj] = MFMA16(aF[ti], bF[tj], acc[ti][tj]);
    }
  }
}

__global__ __launch_bounds__(256) void gemm1_bf_k(
    const unsigned short* __restrict__ Qt, const unsigned short* __restrict__ Kt,
    const float* __restrict__ mask, unsigned short* __restrict__ t0,
    unsigned short* __restrict__ t1, unsigned short* __restrict__ t2,
    unsigned short* __restrict__ t3, float* __restrict__ rowsum) {
  int b = blockIdx.z;
  unsigned short* tbb = (b == 0) ? t0 : (b == 1) ? t1 : (b == 2) ? t2 : t3;
  int i0 = blockIdx.y * 128;
  int j0 = blockIdx.x * 128;
  __shared__ unsigned short sA[8192];
  __shared__ unsigned short sB[8192];
  f32x4 acc[4][4] = {};
  gemm_mainloop64(Qt + (size_t)b * L_ * C_ + (size_t)i0 * C_,
                  Kt + (size_t)b * L_ * C_ + (size_t)j0 * C_, C_, C_, C_, sA,
                  sB, acc);
  int t = threadIdx.x;
  int lane = t & 63;
  int quad = lane >> 4;
  int l15 = lane & 15;
  int w = t >> 6;
  int wm = (w & 1) * 64;
  int wn = (w >> 1) * 64;
  const float scale = 0.04419417382415922f;
  float lm[4], mv[4];
#pragma unroll
  for (int tj = 0; tj < 4; ++tj) {
    int j = j0 + wn + tj * 16 + l15;
    float m = mask[(size_t)b * L_ + j];
    mv[tj] = m;
    lm[tj] = __logf(m + 1e-6f);
  }
  float rs[16];
#pragma unroll
  for (int q = 0; q < 16; ++q) rs[q] = 0.f;
#pragma unroll
  for (int ti = 0; ti < 4; ++ti) {
    int irow = i0 + wm + ti * 16 + quad * 4;
#pragma unroll
    for (int r = 0; r < 4; ++r) {
      size_t ro = (size_t)(irow + r) * L_;
#pragma unroll
      for (int tj = 0; tj < 4; ++tj) {
        float x = fminf(acc[ti][tj][r] * scale + lm[tj], 60.f);
        float tv = __expf(x);
        rs[ti * 4 + r] += tv;
        tbb[ro + j0 + wn + tj * 16 + l15] = f2bf_rne(tv * mv[tj]);
      }
    }
  }
#pragma unroll
  for (int m = 1; m < 16; m <<= 1)
#pragma unroll
    for (int q = 0; q < 16; ++q) rs[q] += __shfl_xor(rs[q], m, 64);
  if (l15 == 0) {
    float* rb = rowsum + (size_t)b * L_ + i0 + wm;
#pragma unroll
    for (int ti = 0; ti < 4; ++ti)
#pragma unroll
      for (int r = 0; r < 4; ++r)
        atomicAdd(&rb[ti * 16 + quad * 4 + r], rs[ti * 4 + r]);
  }
}

__global__ __launch_bounds__(256) void gemm2_bf_k(
    const unsigned short* __restrict__ Vb, const unsigned short* __restrict__ t0,
    const unsigned short* __restrict__ t1, const unsigned short* __restrict__ t2,
    const unsigned short* __restrict__ t3, const float* __restrict__ rowsum,
    float* __restrict__ out) {
  int z = blockIdx.z;
  int b = z & 3;
  int ks = z >> 2;
  const unsigned short* tbb =
      (b == 0) ? t0 : (b == 1) ? t1 : (b == 2) ? t2 : t3;
  int c0 = blockIdx.y * 128;
  int i0 = blockIdx.x * 128;
  __shared__ unsigned short sA[8192];
  __shared__ unsigned short sB[8192];
  f32x4 acc[4][4] = {};
  gemm_mainloop64(Vb + (size_t)b * C_ * L_ + (size_t)c0 * L_ + ks * (L_ / 2),
                  tbb + (size_t)i0 * L_ + ks * (L_ / 2), L_, L_, L_ / 2, sA, sB,
                  acc);
  int t = threadIdx.x;
  int lane = t & 63;
  int quad = lane >> 4;
  int l15 = lane & 15;
  int w = t >> 6;
  int wm = (w & 1) * 64;
  int wn = (w >> 1) * 64;
  float invv[4];
#pragma unroll
  for (int tj = 0; tj < 4; ++tj)
    invv[tj] = 1.0f / rowsum[(size_t)b * L_ + i0 + wn + tj * 16 + l15];
  float* ob = out + (size_t)b * C_ * L_;
#pragma unroll
  for (int ti = 0; ti < 4; ++ti) {
    int crow = c0 + wm + ti * 16 + quad * 4;
#pragma unroll
    for (int r = 0; r < 4; ++r) {
      size_t ro = (size_t)(crow + r) * L_;
#pragma unroll
      for (int tj = 0; tj < 4; ++tj)
        atomicAdd(&ob[ro + i0 + wn + tj * 16 + l15],
                  acc[ti][tj][r] * invv[tj]);
    }
  }
}

extern "C" void kernel_launch(void* const* d_in, const int* in_sizes, int n_in,
                              void* d_out, int out_size, void* d_ws,
                              size_t ws_size, hipStream_t stream) {
  const float* Q = (const float*)d_in[0];
  const float* K = (const float*)d_in[1];
  const float* V = (const float*)d_in[2];
  const float* mask = (const float*)d_in[3];

  float* out = (float*)d_out;                // (B,C,L) fp32
  float* attn = out + (size_t)B_ * C_ * L_;  // (B,L,L) fp32

  const size_t NQ = (size_t)B_ * L_ * C_;    // elems per bf16 operand tensor
  const size_t SLOT = (size_t)L_ * L_;       // elems per (L,L) matrix
  unsigned short* Qt = (unsigned short*)d_ws;
  unsigned short* Kt = Qt + NQ;
  unsigned short* Vb = Kt + NQ;
  float* rowsum = (float*)(Vb + NQ);
  unsigned short* wtail = (unsigned short*)(rowsum + (size_t)B_ * L_);

  // tier-1: tb (B,L,L) bf16 + out2 (B,C,L) fp32 in dedicated workspace
  const size_t need1 =
      NQ * 2 * 3 + (size_t)B_ * L_ * 4 + (size_t)B_ * SLOT * 2 + NQ * 4;

  prep_k<<<dim3(64, 8, 12), 256, 0, stream>>>(Q, K, V, mask, Qt, Kt, Vb,
                                              rowsum);

  if (ws_size >= need1) {
    unsigned short* tb = wtail;                      // (B,L,L) bf16
    float* out2 = (float*)(tb + (size_t)B_ * SLOT);  // (B,C,L) fp32
    gemm1_8p_k<<<dim3(16, 16, B_), 512, 0, stream>>>(
        Qt, Kt, mask, tb, tb + SLOT, tb + 2 * SLOT, tb + 3 * SLOT, rowsum);
    gemm2_8p_k<<<dim3(16, 2, B_ * 2), 512, 0, stream>>>(
        Vb, tb, tb + SLOT, tb + 2 * SLOT, tb + 3 * SLOT, rowsum, out, out2);
    finalize_all_k<<<dim3(64, 64, B_), 256, 0, stream>>>(tb, rowsum, attn, out,
                                                         out2);
  } else {
    // fallback tier: tb parked in not-yet-final attn slots (round-1 layout).
    unsigned short* tb0 = (unsigned short*)(attn + 2 * SLOT);
    unsigned short* tb1 = (unsigned short*)(attn + 3 * SLOT);
    unsigned short* tb2 = (unsigned short*)(attn + 3 * SLOT + SLOT / 2);
    unsigned short* tb3 = wtail;
    hipMemsetAsync(out, 0, (size_t)B_ * C_ * L_ * sizeof(float), stream);
    gemm1_bf_k<<<dim3(L_ / 128, L_ / 128, B_), 256, 0, stream>>>(
        Qt, Kt, mask, tb0, tb1, tb2, tb3, rowsum);
    gemm2_bf_k<<<dim3(L_ / 128, C_ / 128, B_ * 2), 256, 0, stream>>>(
        Vb, tb0, tb1, tb2, tb3, rowsum, out);
    finalize_all_k<<<dim3(64, 64, 1), 256, 0, stream>>>(tb0, rowsum, attn,
                                                        nullptr, nullptr);
    finalize_all_k<<<dim3(64, 64, 1), 256, 0, stream>>>(tb1, rowsum + L_,
                                                        attn + SLOT, nullptr,
                                                        nullptr);
    finalize_all_k<<<dim3(64, 64, 1), 256, 0, stream>>>(tb2, rowsum + 2 * L_,
                                                        attn + 2 * SLOT,
                                                        nullptr, nullptr);
    finalize_all_k<<<dim3(64, 64, 1), 256, 0, stream>>>(tb3, rowsum + 3 * L_,
                                                        attn + 3 * SLOT,
                                                        nullptr, nullptr);
  }
}